// Round 1
// 8928.366 us; speedup vs baseline: 1.5849x; 1.5849x over previous
//
#include <hip/hip_runtime.h>
#include <math.h>

// Problem constants
#define B_ 2
#define T_ 1024
#define C_ 768
#define V_ 32000
#define L_ 4
#define NB_ 4
#define K_ 15
#define P_ 16
#define C2_ 384    // C/2
#define C4_ 3072   // 4*C == NB*C
#define CX2_ 1536  // 2*C
#define NCH_ 32    // cumsum chunks
#define CHT_ 32    // T_/NCH_
#define SCALE_F 1.8137993642342178f   // pi/sqrt(3)
#define EPS_F 1.1920929e-07f

typedef __attribute__((ext_vector_type(8))) short short8;
typedef __attribute__((ext_vector_type(4))) float f32x4;

__device__ __forceinline__ float sigmoidf_(float x){ return 1.0f/(1.0f+expf(-x)); }
__device__ __forceinline__ float leluf_(float x){ return x*sigmoidf_(SCALE_F*x); }
__device__ __forceinline__ float softplusf_(float x){ return (x>20.f)?x:log1pf(expf(x)); }

__device__ __forceinline__ unsigned short f2bf(float f){
  unsigned int u = __float_as_uint(f);
  u = u + 0x7FFF + ((u>>16)&1u);
  return (unsigned short)(u>>16);
}
__device__ __forceinline__ float bf2f(unsigned short h){ return __uint_as_float(((unsigned int)h)<<16); }

__device__ __forceinline__ float block_reduce_sum_256(float v){
  __shared__ float red[4];
  #pragma unroll
  for (int o=32;o;o>>=1) v += __shfl_down(v,o);
  if ((threadIdx.x&63)==0) red[threadIdx.x>>6]=v;
  __syncthreads();
  float r = red[0]+red[1]+red[2]+red[3];
  __syncthreads();
  return r;
}

// ---------------- basic kernels ----------------

__global__ void sincos_kernel(float* __restrict__ cosb, float* __restrict__ sinb){
  int i = blockIdx.x*256 + threadIdx.x;       // T_*C2_
  int t = i / C2_, j = i % C2_;
  float inv = 1.0f / powf(10000.0f, (2.0f*(float)j)/(float)C_);
  float fr = (float)t * inv;
  cosb[i] = cosf(fr);
  sinb[i] = sinf(fr);
}

__global__ void embed_kernel(const int* __restrict__ idx, const float* __restrict__ wte,
                             float* __restrict__ x){
  int i = blockIdx.x*256 + threadIdx.x;       // B_*T_*C_
  int c = i % C_; int bt = i / C_;
  x[i] = wte[(size_t)idx[bt]*C_ + c];
}

__global__ __launch_bounds__(256) void rmsnorm_kernel(const float* __restrict__ in,
                                                      float* __restrict__ out){
  int row = blockIdx.x;
  const float* p = in + (size_t)row*C_;
  float s = 0.f;
  for (int c = threadIdx.x; c < C_; c += 256){ float v = p[c]; s += v*v; }
  float tot = block_reduce_sum_256(s);
  float scale = rsqrtf(tot/(float)C_ + EPS_F);
  float* o = out + (size_t)row*C_;
  for (int c = threadIdx.x; c < C_; c += 256) o[c] = p[c]*scale;
}

__global__ void conv_kernel(const float* __restrict__ nx, const float* __restrict__ cw,
                            float* __restrict__ xs){
  int i = blockIdx.x*256 + threadIdx.x;       // B_*T_*C_
  int c = i % C_;
  int t = (i / C_) % T_;
  int b = i / (C_*T_);
  float s = 0.f;
  #pragma unroll
  for (int j=0;j<K_;j++){
    int tt = t + j - (K_-1);
    if (tt >= 0) s += nx[((size_t)(b*T_+tt))*C_ + c] * cw[c*K_ + j];
  }
  xs[i] = s;
}

// coords = tanh(h384 @ nw2), one 64-thread wave per row
__global__ __launch_bounds__(64) void coords_kernel(const float* __restrict__ h,
                                                    const float* __restrict__ nw2,
                                                    float* __restrict__ coords){
  int row = blockIdx.x; int lane = threadIdx.x;
  const float* p = h + (size_t)row*C2_;
  float s0=0.f, s1=0.f;
  for (int j=lane;j<C2_;j+=64){ float v=p[j]; s0 += v*nw2[j*2]; s1 += v*nw2[j*2+1]; }
  #pragma unroll
  for (int o=32;o;o>>=1){ s0 += __shfl_down(s0,o); s1 += __shfl_down(s1,o); }
  if (lane==0){ coords[row*2]=tanhf(s0); coords[row*2+1]=tanhf(s1); }
}

__global__ __launch_bounds__(256) void sample_kernel(const float* __restrict__ coords,
                                                     const float* __restrict__ pal,
                                                     float* __restrict__ ret){
  int row = blockIdx.x;
  float cx = coords[row*2], cy = coords[row*2+1];
  float ix = fminf(fmaxf((cx+1.f)*0.5f*(float)(P_-1), 0.f), (float)(P_-1));
  float iy = fminf(fmaxf((cy+1.f)*0.5f*(float)(P_-1), 0.f), (float)(P_-1));
  float x0f = floorf(ix), y0f = floorf(iy);
  float wx = ix-x0f, wy = iy-y0f;
  int x0 = (int)x0f, y0 = (int)y0f;
  int x1 = min(x0+1, P_-1), y1 = min(y0+1, P_-1);
  float w00=(1.f-wx)*(1.f-wy), w01=wx*(1.f-wy), w10=(1.f-wx)*wy, w11=wx*wy;
  float* o = ret + (size_t)row*C_;
  for (int c=threadIdx.x;c<C_;c+=256){
    const float* pc = pal + (size_t)c*(P_*P_);
    o[c] = pc[y0*P_+x0]*w00 + pc[y0*P_+x1]*w01 + pc[y1*P_+x0]*w10 + pc[y1*P_+x1]*w11;
  }
}

// q head rows: rmsnorm over C then RoPE; in (B,T,NB,C) -> out (B,NB,T,C)
__global__ __launch_bounds__(256) void qnorm_rope_kernel(const float* __restrict__ qp,
                                                         const float* __restrict__ cosb,
                                                         const float* __restrict__ sinb,
                                                         float* __restrict__ qn){
  int blk = blockIdx.x;          // (b*T+t)*NB + n
  int n = blk % NB_;
  int bt = blk / NB_;
  int t = bt % T_;
  int b = bt / T_;
  const float* p = qp + (size_t)blk*C_;
  float s=0.f;
  for (int c=threadIdx.x;c<C_;c+=256){ float v=p[c]; s+=v*v; }
  float tot = block_reduce_sum_256(s);
  float scale = rsqrtf(tot/(float)C_ + EPS_F);
  float* o = qn + (((size_t)(b*NB_+n))*T_ + t)*C_;
  for (int i=threadIdx.x;i<C2_;i+=256){
    float x1v = p[2*i]*scale, x2v = p[2*i+1]*scale;
    float cs = cosb[t*C2_+i], sn = sinb[t*C2_+i];
    o[2*i]   = x1v*cs - x2v*sn;
    o[2*i+1] = x1v*sn + x2v*cs;
  }
}

__global__ void rope_k_kernel(float* __restrict__ k, const float* __restrict__ cosb,
                              const float* __restrict__ sinb){
  int i = blockIdx.x*256 + threadIdx.x;  // B_*T_*C2_
  int j = i % C2_;
  int bt = i / C2_;
  int t = bt % T_;
  float* p = k + (size_t)bt*C_;
  float x1v = p[2*j], x2v = p[2*j+1];
  float cs = cosb[t*C2_+j], sn = sinb[t*C2_+j];
  p[2*j]   = x1v*cs - x2v*sn;
  p[2*j+1] = x1v*sn + x2v*cs;
}

// ---------------- split-bf16 conversion ----------------
// A (M,Kd) f32 -> A2 (M, 2*Kd) bf16: [Ah | Al]
__global__ void convA_kernel(const float* __restrict__ A, unsigned short* __restrict__ A2, int Kd){
  int i = blockIdx.x*256 + threadIdx.x;
  int m = i / Kd, k = i % Kd;
  float a = A[i];
  unsigned short h = f2bf(a);
  unsigned short l = f2bf(a - bf2f(h));
  size_t base = (size_t)m*(2*Kd);
  A2[base + k] = h;
  A2[base + Kd + k] = l;
}

// W (Kd, Nfull) f32, columns [n_start, n_start+len) -> W2T (len, 2*Kd) bf16: [Wh | Wl], transposed
__global__ __launch_bounds__(256) void convWT_kernel(const float* __restrict__ W,
                                                     unsigned short* __restrict__ W2T,
                                                     int Kd, int Nfull, int n_start){
  __shared__ float tile[32][33];
  int tx = threadIdx.x & 31, ty = threadIdx.x >> 5;   // 32x8
  int k0 = blockIdx.y*32, nl0 = blockIdx.x*32;
  #pragma unroll
  for (int r=0;r<4;r++)
    tile[ty + r*8][tx] = W[(size_t)(k0 + ty + r*8)*Nfull + n_start + nl0 + tx];
  __syncthreads();
  #pragma unroll
  for (int r=0;r<4;r++){
    int nl = nl0 + ty + r*8;
    int k  = k0 + tx;
    float v = tile[tx][ty + r*8];
    unsigned short h = f2bf(v);
    unsigned short l = f2bf(v - bf2f(h));
    size_t base = (size_t)nl*(2*Kd);
    W2T[base + k] = h;
    W2T[base + Kd + k] = l;
  }
}

// ---------------- MFMA split-bf16 GEMM ----------------
// out = act(A @ W) [+ add], via Ah*Wh + Al*Wh + Ah*Wl
// A2 (M,2K) [Ah|Al], W2T (N,2K) rows=[Wh|Wl]. BM=BN=128, BK=32.
// MODE 0: dense. MODE 1: causal row-skip (scores: skip tile if n0 > t_low).
// MODE 2: causal K-cap (PV: only K < (m0+128)*NB contributes).
// blockIdx.z batches with element strides zA/zW/zO.
__device__ __forceinline__ void gload16(const void* g, void* l){
  __builtin_amdgcn_global_load_lds((const __attribute__((address_space(1))) unsigned int*)g,
                                   (__attribute__((address_space(3))) unsigned int*)l, 16, 0, 0);
}

template<int ACT, bool ADD, int MODE>
__global__ __launch_bounds__(256) void gemm_split_kernel(const unsigned short* __restrict__ A2,
                                                         const unsigned short* __restrict__ W2T,
                                                         const float* __restrict__ add,
                                                         float* __restrict__ out,
                                                         int Kd, int ldo,
                                                         long zA, long zW, long zO){
  int m0 = blockIdx.y * 128;
  int n0 = blockIdx.x * 128;
  if (MODE==1){ if (n0 > (m0 & (T_-1))) return; }
  A2  += (size_t)blockIdx.z * zA;
  W2T += (size_t)blockIdx.z * zW;
  out += (size_t)blockIdx.z * zO;
  if (ADD) add += (size_t)blockIdx.z * zO;
  __shared__ char lds[16384];
  char* As = lds;
  char* Bs = lds + 8192;
  int tid = threadIdx.x;
  int wave = tid >> 6, lane = tid & 63;
  int q = lane >> 4, mr = lane & 15;
  int K2 = 2*Kd;
  f32x4 acc[4][4] = {};
  int wm = (wave >> 1) * 64;
  int wn = (wave & 1) * 64;
  int sA = wave*2;
  int Kc = Kd;
  if (MODE==2){ int cap = (m0+128)*NB_; if (cap < Kd) Kc = cap; }
  for (int seg = 0; seg < 3; seg++){
    int aK = (seg==1) ? Kd : 0;
    int wK = (seg==2) ? Kd : 0;
    for (int rr = 0; rr < Kc; rr += 32){
      int aoff = aK + rr;
      int woff = wK + rr;
      #pragma unroll
      for (int e=0;e<2;e++){
        int st = sA + e;
        const unsigned short* ga = A2 + (size_t)(m0 + st*16 + mr)*K2 + aoff + q*8;
        gload16(ga, As + st*1024 + lane*16);
        const unsigned short* gb = W2T + (size_t)(n0 + st*16 + mr)*K2 + woff + q*8;
        gload16(gb, Bs + st*1024 + lane*16);
      }
      __syncthreads();
      short8 af[4], bfr[4];
      #pragma unroll
      for (int i=0;i<4;i++){
        af[i]  = *(const short8*)(As + ((wm>>4) + i)*1024 + q*256 + mr*16);
        bfr[i] = *(const short8*)(Bs + ((wn>>4) + i)*1024 + q*256 + mr*16);
      }
      #pragma unroll
      for (int i=0;i<4;i++)
        #pragma unroll
        for (int j=0;j<4;j++)
          acc[i][j] = __builtin_amdgcn_mfma_f32_16x16x32_bf16(af[i], bfr[j], acc[i][j], 0, 0, 0);
      __syncthreads();
    }
  }
  #pragma unroll
  for (int i=0;i<4;i++){
    int row0 = m0 + wm + i*16 + q*4;
    #pragma unroll
    for (int j=0;j<4;j++){
      int col = n0 + wn + j*16 + mr;
      #pragma unroll
      for (int r2=0;r2<4;r2++){
        float v = acc[i][j][r2];
        if (ACT==1) v = leluf_(v);
        if (ADD) v += add[(size_t)(row0+r2)*ldo + col];
        out[(size_t)(row0+r2)*ldo + col] = v;
      }
    }
  }
}

// ---------------- attention routing ----------------
// scores (B, NB*T, T): row (n*T+t) within batch b, col s. Compute per (b,t):
//   m_s = max_n score, msk = heads at max, sp = softplus(m), factor, resid, flags
//   comb[bt][s*4+n] = msk ? sp*factor : 0   (0 for s>t)
__global__ __launch_bounds__(256) void route_kernel(const float* __restrict__ scores,
                                                    float* __restrict__ comb,
                                                    float* __restrict__ residb,
                                                    unsigned char* __restrict__ flagsb){
  __shared__ unsigned int flagred;
  int bt = blockIdx.x;
  int b = bt / T_, t = bt % T_;
  int tid = threadIdx.x;
  if (tid==0) flagred = 0u;
  __syncthreads();
  const float invsq = 0.03608439182435161f; // 1/sqrt(768)
  const float* sp0 = scores + ((size_t)b*NB_*T_ + t)*T_;   // head 0 row
  const size_t hp = (size_t)T_*T_;                          // head pitch
  float w[4]; unsigned int mk[4];
  float lsum = 0.f; unsigned int lflags = 0u;
  #pragma unroll
  for (int r=0;r<4;r++){
    int s = tid + r*256;
    float a0 = sp0[s]*invsq;
    float a1 = sp0[hp + s]*invsq;
    float a2 = sp0[2*hp + s]*invsq;
    float a3 = sp0[3*hp + s]*invsq;
    float m = fmaxf(fmaxf(a0,a1), fmaxf(a2,a3));
    unsigned int msk = (unsigned int)(a0==m) | ((unsigned int)(a1==m)<<1)
                     | ((unsigned int)(a2==m)<<2) | ((unsigned int)(a3==m)<<3);
    float spv = softplusf_(m);
    if (s > t){ spv = 0.f; msk = 0u; }
    w[r] = spv; mk[r] = msk;
    lsum += spv; lflags |= msk;
  }
  if (t == T_-1) atomicOr(&flagred, lflags);
  float ssum = block_reduce_sum_256(lsum);
  float factor = fminf(1.0f/(ssum + 1e-6f), 1.0f);
  float* crow = comb + (size_t)bt*(NB_*T_);
  #pragma unroll
  for (int r=0;r<4;r++){
    int s = tid + r*256;
    float wv = w[r]*factor;
    f32x4 o;
    o[0] = (mk[r]&1u) ? wv : 0.f;
    o[1] = (mk[r]&2u) ? wv : 0.f;
    o[2] = (mk[r]&4u) ? wv : 0.f;
    o[3] = (mk[r]&8u) ? wv : 0.f;
    *(f32x4*)(crow + (size_t)s*4) = o;
  }
  if (tid==0){
    residb[bt] = 1.0f - ssum*factor;
    flagsb[bt] = (t < T_-1) ? (unsigned char)0xF : (unsigned char)flagred;
  }
}

// y[bt,c] += resid[bt]*sr[c] + sum_{n in flags} sb[n,c]
__global__ void sink_kernel(float* __restrict__ y, const float* __restrict__ sr,
                            const float* __restrict__ sb,
                            const float* __restrict__ residb,
                            const unsigned char* __restrict__ flagsb){
  int i = blockIdx.x*256 + threadIdx.x;  // B_*T_*C_
  int c = i % C_; int bt = i / C_;
  unsigned int f = flagsb[bt];
  float add = residb[bt]*sr[c];
  #pragma unroll
  for (int n=0;n<NB_;n++) if (f & (1u<<n)) add += sb[n*C_ + c];
  y[i] += add;
}

// ---------------- chunked cumulative mean ----------------
__global__ void cumsum_part_kernel(const float* __restrict__ na, float* __restrict__ part){
  int i = blockIdx.x*256 + threadIdx.x;  // B_*NCH_*C_
  int c = i % C_; int bc = i / C_; int ch = bc % NCH_; int b = bc / NCH_;
  const float* p = na + ((size_t)(b*T_ + ch*CHT_))*C_ + c;
  float s = 0.f;
  #pragma unroll 4
  for (int t=0;t<CHT_;t++) s += p[(size_t)t*C_];
  part[i] = s;
}
__global__ void cumsum_scan_kernel(float* __restrict__ part){
  int i = blockIdx.x*256 + threadIdx.x;  // B_*C_
  int c = i % C_; int b = i / C_;
  float run = 0.f;
  for (int ch=0; ch<NCH_; ch++){
    size_t off = ((size_t)b*NCH_ + ch)*C_ + c;
    float v = part[off]; part[off] = run; run += v;
  }
}
__global__ void cumsum_apply_kernel(const float* __restrict__ na, const float* __restrict__ part,
                                    float* __restrict__ x){
  int i = blockIdx.x*256 + threadIdx.x;  // B_*NCH_*C_
  int c = i % C_; int bc = i / C_; int ch = bc % NCH_; int b = bc / NCH_;
  float run = part[i];
  int t0 = ch*CHT_;
  size_t base = ((size_t)(b*T_) + t0)*C_ + c;
  for (int t=0;t<CHT_;t++){
    run += na[base + (size_t)t*C_];
    x[base + (size_t)t*C_] += run / (float)(t0 + t + 1);
  }
}

// ---------------- launch ----------------

static inline void convA(const float* A, unsigned short* A2, int Kd, hipStream_t s){
  convA_kernel<<<(B_*T_*Kd)/256, 256, 0, s>>>(A, A2, Kd);
}
static inline void convW(const float* W, unsigned short* W2T, int Kd, int Nfull, int n_start,
                         int n_len, hipStream_t s){
  dim3 g(n_len/32, Kd/32);
  convWT_kernel<<<g, 256, 0, s>>>(W, W2T, Kd, Nfull, n_start);
}
static inline void gemm(const unsigned short* A2, const unsigned short* W2T, const float* add,
                        float* out, int N, int Kd, int act, hipStream_t s){
  dim3 g(N/128, (B_*T_)/128);
  if (act)      gemm_split_kernel<1,false,0><<<g,256,0,s>>>(A2,W2T,nullptr,out,Kd,N,0,0,0);
  else if (add) gemm_split_kernel<0,true ,0><<<g,256,0,s>>>(A2,W2T,add,out,Kd,N,0,0,0);
  else          gemm_split_kernel<0,false,0><<<g,256,0,s>>>(A2,W2T,nullptr,out,Kd,N,0,0,0);
}

extern "C" void kernel_launch(void* const* d_in, const int* in_sizes, int n_in,
                              void* d_out, int out_size, void* d_ws, size_t ws_size,
                              hipStream_t stream){
  (void)in_sizes; (void)n_in; (void)out_size; (void)ws_size;
  const int*   idx      = (const int*)  d_in[0];
  const float* wte      = (const float*)d_in[1];
  const float* lm_head  = (const float*)d_in[2];
  const float* q_w      = (const float*)d_in[3];
  const float* k_w      = (const float*)d_in[4];
  const float* v_w      = (const float*)d_in[5];
  const float* o_w      = (const float*)d_in[6];
  const float* sink_res = (const float*)d_in[7];
  const float* sink_bas = (const float*)d_in[8];
  const float* palette  = (const float*)d_in[9];
  const float* conv_w   = (const float*)d_in[10];
  const float* nav_w1   = (const float*)d_in[11];
  const float* nav_w2   = (const float*)d_in[12];
  const float* out_w1   = (const float*)d_in[13];
  const float* out_w2   = (const float*)d_in[14];
  const float* mlp1_fc  = (const float*)d_in[15];
  const float* mlp1_pj  = (const float*)d_in[16];
  const float* mlp2_fc  = (const float*)d_in[17];
  const float* mlp2_pj  = (const float*)d_in[18];
  float* out = (float*)d_out;

  char* wsb = (char*)d_ws;
  size_t off = 0;
  auto allocb = [&](size_t bytes){ void* p = wsb + off; off += (bytes + 255) & ~255ULL; return p; };
  const size_t BT = (size_t)B_*T_, BTC = BT*C_;
  float* cosb  = (float*)allocb(T_*C2_*4);
  float* sinb  = (float*)allocb(T_*C2_*4);
  float* x     = (float*)allocb(BTC*4);
  float* ntmp  = (float*)allocb(BTC*4);
  float* na    = (float*)allocb(BTC*4);
  float* kb    = (float*)allocb(BTC*4);
  float* xs    = (float*)allocb(BTC*4);
  float* h384  = (float*)allocb(BT*C2_*4);
  float* crd   = (float*)allocb(BT*2*4);
  float* h1536 = (float*)allocb(BT*CX2_*4);
  float* qb    = (float*)allocb(BTC*4);
  float* ab    = (float*)allocb(BTC*4);
  float* hbig  = (float*)allocb(BT*C4_*4);
  float* qnb   = (float*)allocb(BT*C4_*4);
  float* vb    = (float*)allocb(BT*C4_*4);
  float* yb    = (float*)allocb(BTC*4);
  float* ub    = (float*)allocb(BTC*4);
  unsigned short* A2  = (unsigned short*)allocb((size_t)2048*6144*2);   // 25.2 MB
  unsigned short* W2T = (unsigned short*)allocb((size_t)8192*1536*2);   // 25.2 MB
  float* residb = (float*)allocb(BT*4);
  unsigned char* flagsb = (unsigned char*)allocb(BT);
  float* part = (float*)allocb((size_t)B_*NCH_*C_*4);

  // Aliased attention buffers (regions dead during attention phase):
  unsigned short* k2    = (unsigned short*)xs;    // 6.3 MB (k in W2T-format)
  float*          scores= (float*)hbig;           // 33.5 MB over hbig..qnb (dead)
  float*          comb  = xs;                     // 33.5 MB over xs..ab (dead)
  unsigned short* comb2 = (unsigned short*)hbig;  // 33.5 MB over scores (consumed)
  unsigned short* v2T   = W2T;                    // 25.2 MB

  sincos_kernel<<<(T_*C2_)/256, 256, 0, stream>>>(cosb, sinb);
  embed_kernel<<<BTC/256, 256, 0, stream>>>(idx, wte, x);

  const int M = B_*T_;
  for (int l = 0; l < L_; l++){
    const float* qw  = q_w     + (size_t)l*C_*C4_;
    const float* kw  = k_w     + (size_t)l*C_*C_;
    const float* vw  = v_w     + (size_t)l*C_*C4_;
    const float* ow  = o_w     + (size_t)l*C_*C_;
    const float* sr  = sink_res+ (size_t)l*C_;
    const float* sb  = sink_bas+ (size_t)l*NB_*C_;
    const float* pal = palette + (size_t)l*C_*P_*P_;
    const float* cw  = conv_w  + (size_t)l*C_*K_;
    const float* nw1 = nav_w1  + (size_t)l*C_*C2_;
    const float* nw2 = nav_w2  + (size_t)l*C2_*2;
    const float* ow1 = out_w1  + (size_t)l*C_*CX2_;
    const float* ow2 = out_w2  + (size_t)l*CX2_*C_;
    const float* fc1 = mlp1_fc + (size_t)l*C_*C4_;
    const float* pj1 = mlp1_pj + (size_t)l*C4_*C_;
    const float* fc2 = mlp2_fc + (size_t)l*C_*C4_;
    const float* pj2 = mlp2_pj + (size_t)l*C4_*C_;

    rmsnorm_kernel<<<M, 256, 0, stream>>>(x, ntmp);                  // nx
    convA(ntmp, A2, C_, stream);
    convW(kw, W2T, C_, C_, 0, C_, stream);
    gemm(A2, W2T, nullptr, kb, C_, C_, 0, stream);                   // k = nx@kw
    rope_k_kernel<<<(M*C2_)/256, 256, 0, stream>>>(kb, cosb, sinb);
    conv_kernel<<<BTC/256, 256, 0, stream>>>(ntmp, cw, xs);          // depthwise conv
    convA(xs, A2, C_, stream);
    convW(nw1, W2T, C_, C2_, 0, C2_, stream);
    gemm(A2, W2T, nullptr, h384, C2_, C_, 1, stream);                // lelu(xs@nw1)
    coords_kernel<<<M, 64, 0, stream>>>(h384, nw2, crd);
    sample_kernel<<<M, 256, 0, stream>>>(crd, pal, xs);              // ret (reuse xs)
    convA(xs, A2, C_, stream);
    convW(ow1, W2T, C_, CX2_, 0, CX2_, stream);
    gemm(A2, W2T, nullptr, h1536, CX2_, C_, 1, stream);              // lelu(ret@ow1)
    convA(h1536, A2, CX2_, stream);
    convW(ow2, W2T, CX2_, C_, 0, C_, stream);
    gemm(A2, W2T, nullptr, qb, C_, CX2_, 0, stream);                 // q
    rmsnorm_kernel<<<M, 256, 0, stream>>>(qb, ntmp);                 // nq
    convA(ntmp, A2, C_, stream);
    convW(fc1, W2T, C_, C4_, 0, C4_, stream);
    gemm(A2, W2T, nullptr, hbig, C4_, C_, 1, stream);                // lelu(nq@fc1)
    convA(hbig, A2, C4_, stream);
    convW(pj1, W2T, C4_, C_, 0, C_, stream);
    gemm(A2, W2T, qb, ab, C_, C4_, 0, stream);                       // a = q + h@pj1
    rmsnorm_kernel<<<M, 256, 0, stream>>>(ab, na);                   // na
    convA(na, A2, C_, stream);
    convW(qw, W2T, C_, C4_, 0, C4_, stream);
    gemm(A2, W2T, nullptr, hbig, C4_, C_, 0, stream);                // qproj
    qnorm_rope_kernel<<<M*NB_, 256, 0, stream>>>(hbig, cosb, sinb, qnb);
    convW(vw, W2T, C_, C4_, 0, C4_, stream);
    gemm(A2, W2T, nullptr, vb, C4_, C_, 0, stream);                  // v (A2 still = na)

    // ---- attention via MFMA ----
    convA_kernel<<<(M*C_)/256, 256, 0, stream>>>(kb, k2, C_);        // k -> W2T format
    convA_kernel<<<(B_*NB_*T_*C_)/256, 256, 0, stream>>>(qnb, A2, C_); // qn -> A2 (8192 rows)
    { dim3 g(T_/128, (NB_*T_)/128, B_);                              // scores = qn @ k^T
      gemm_split_kernel<0,false,1><<<g,256,0,stream>>>(A2, k2, nullptr, scores, C_, T_,
          (long)NB_*T_*2*C_, (long)T_*2*C_, (long)NB_*T_*T_); }
    route_kernel<<<M, 256, 0, stream>>>(scores, comb, residb, flagsb);
    for (int b2 = 0; b2 < B_; b2++){                                 // v -> W2T format (transpose)
      dim3 g(C_/32, (NB_*T_)/32);
      convWT_kernel<<<g,256,0,stream>>>(vb + (size_t)b2*NB_*T_*C_,
                                        v2T + (size_t)b2*C_*2*NB_*T_,
                                        NB_*T_, C_, 0);
    }
    convA_kernel<<<(M*NB_*T_)/256, 256, 0, stream>>>(comb, comb2, NB_*T_);
    { dim3 g(C_/128, T_/128, B_);                                    // y_ctx = comb @ v
      gemm_split_kernel<0,false,2><<<g,256,0,stream>>>(comb2, v2T, nullptr, yb, NB_*T_, C_,
          (long)T_*2*NB_*T_, (long)C_*2*NB_*T_, (long)T_*C_); }
    sink_kernel<<<BTC/256, 256, 0, stream>>>(yb, sr, sb, residb, flagsb);

    convA(yb, A2, C_, stream);
    convW(ow, W2T, C_, C_, 0, C_, stream);
    gemm(A2, W2T, x, ub, C_, C_, 0, stream);                         // u = x + y@ow
    rmsnorm_kernel<<<M, 256, 0, stream>>>(ub, ntmp);                 // nu
    convA(ntmp, A2, C_, stream);
    convW(fc2, W2T, C_, C4_, 0, C4_, stream);
    gemm(A2, W2T, nullptr, hbig, C4_, C_, 1, stream);                // lelu(nu@fc2)
    convA(hbig, A2, C4_, stream);
    convW(pj2, W2T, C4_, C_, 0, C_, stream);
    gemm(A2, W2T, ub, x, C_, C4_, 0, stream);                        // u2 = u + h@pj2 -> x
    cumsum_part_kernel<<<(B_*NCH_*C_)/256, 256, 0, stream>>>(na, part);
    cumsum_scan_kernel<<<(B_*C_)/256, 256, 0, stream>>>(part);
    cumsum_apply_kernel<<<(B_*NCH_*C_)/256, 256, 0, stream>>>(na, part, x);
  }

  rmsnorm_kernel<<<M, 256, 0, stream>>>(x, ntmp);
  convA(ntmp, A2, C_, stream);
  for (int n0 = 0; n0 < V_; n0 += 8192){
    int len = (V_ - n0 < 8192) ? (V_ - n0) : 8192;
    convW(lm_head, W2T, C_, V_, n0, len, stream);
    dim3 g(len/128, M/128);
    gemm_split_kernel<0,false,0><<<g,256,0,stream>>>(A2, W2T, nullptr, out + n0, C_, V_, 0,0,0);
  }
}